// Round 2
// baseline (577.899 us; speedup 1.0000x reference)
//
#include <hip/hip_runtime.h>

#define BN_EPS 1e-5f
#define NBUF 64   // spread buffers for stat atomics

// ---------------------------------------------------------------------------
// Fused gather + GEMM + partial BN-stats kernel.
// One thread = one node (and one COUT_TILE slice of output channels).
// W tile staged in LDS; inner reads are wave-uniform (broadcast, conflict-free).
// Grid: (N/256, COUT_TOTAL/COUT_TILE), block 256. N must be divisible by 256.
// ---------------------------------------------------------------------------
template<int CIN, int COUT_TILE, int COUT_TOTAL>
__global__ void __launch_bounds__(256) conv_kernel(
    const float* __restrict__ x, const int* __restrict__ neigh,
    const float* __restrict__ W, float* __restrict__ y,
    float* __restrict__ stats)
{
    __shared__ float Wlds[27 * CIN * COUT_TILE];
    const int cobase = blockIdx.y * COUT_TILE;

    for (int i = threadIdx.x; i < 27 * CIN * COUT_TILE; i += 256) {
        int k = i / COUT_TILE, c = i - k * COUT_TILE;
        Wlds[i] = W[k * COUT_TOTAL + cobase + c];
    }
    __syncthreads();

    const int node = blockIdx.x * 256 + threadIdx.x;

    float acc[COUT_TILE];
#pragma unroll
    for (int c = 0; c < COUT_TILE; ++c) acc[c] = 0.f;

    const int* nrow = neigh + (size_t)node * 27;
#pragma unroll 1
    for (int j = 0; j < 27; ++j) {
        const int nb = nrow[j];
        const float4* xr = (const float4*)(x + (size_t)nb * CIN);
#pragma unroll
        for (int k4 = 0; k4 < CIN / 4; ++k4) {
            const float4 xq = xr[k4];
#pragma unroll
            for (int kk = 0; kk < 4; ++kk) {
                const float xv = (kk == 0) ? xq.x : (kk == 1) ? xq.y : (kk == 2) ? xq.z : xq.w;
                const float4* wv = (const float4*)&Wlds[(j * CIN + k4 * 4 + kk) * COUT_TILE];
#pragma unroll
                for (int c4 = 0; c4 < COUT_TILE / 4; ++c4) {
                    const float4 w = wv[c4];
                    acc[c4 * 4 + 0] = fmaf(xv, w.x, acc[c4 * 4 + 0]);
                    acc[c4 * 4 + 1] = fmaf(xv, w.y, acc[c4 * 4 + 1]);
                    acc[c4 * 4 + 2] = fmaf(xv, w.z, acc[c4 * 4 + 2]);
                    acc[c4 * 4 + 3] = fmaf(xv, w.w, acc[c4 * 4 + 3]);
                }
            }
        }
    }

    // write raw GEMM output
    float4* yr = (float4*)(y + (size_t)node * COUT_TOTAL + cobase);
#pragma unroll
    for (int c4 = 0; c4 < COUT_TILE / 4; ++c4)
        yr[c4] = make_float4(acc[c4 * 4 + 0], acc[c4 * 4 + 1], acc[c4 * 4 + 2], acc[c4 * 4 + 3]);

    // per-channel partial sums (wave tree reduce -> spread atomics)
    float* buf = stats + (blockIdx.x & (NBUF - 1)) * (2 * COUT_TOTAL);
#pragma unroll
    for (int c = 0; c < COUT_TILE; ++c) {
        float v = acc[c];
        float q = v * v;
#pragma unroll
        for (int off = 32; off > 0; off >>= 1) {
            v += __shfl_xor(v, off, 64);
            q += __shfl_xor(q, off, 64);
        }
        if ((threadIdx.x & 63) == 0) {
            atomicAdd(&buf[cobase + c], v);
            atomicAdd(&buf[COUT_TOTAL + cobase + c], q);
        }
    }
}

// ---------------------------------------------------------------------------
// Fold BN stats + gamma/beta into per-channel scale/shift.
// ---------------------------------------------------------------------------
__global__ void finalize_kernel(const float* __restrict__ stats,
                                const float* __restrict__ gamma,
                                const float* __restrict__ beta,
                                float* __restrict__ ss, int COUT, float invN)
{
    const int c = threadIdx.x;
    if (c >= COUT) return;
    float s = 0.f, q = 0.f;
    for (int b = 0; b < NBUF; ++b) {
        s += stats[b * 2 * COUT + c];
        q += stats[b * 2 * COUT + COUT + c];
    }
    const float mean = s * invN;
    const float var  = fmaf(-mean, mean, q * invN);
    const float sc   = gamma[c] * rsqrtf(var + BN_EPS);
    ss[c]        = sc;
    ss[COUT + c] = fmaf(-mean, sc, beta[c]);
}

// ---------------------------------------------------------------------------
// affine (BN) + ReLU + 8-sibling max pool.  thread t -> (parent p, channel c)
// ---------------------------------------------------------------------------
template<int COUT>
__global__ void __launch_bounds__(256) pool_kernel(
    const float* __restrict__ y, const float* __restrict__ ss,
    float* __restrict__ xout, int total)
{
    const int t = blockIdx.x * 256 + threadIdx.x;
    if (t >= total) return;
    const int p = t / COUT, c = t % COUT;
    const float sc = ss[c], sh = ss[COUT + c];
    const float* yr = y + (size_t)p * 8 * COUT + c;
    float m = -3.4e38f;
#pragma unroll
    for (int i = 0; i < 8; ++i) m = fmaxf(m, fmaf(yr[i * COUT], sc, sh));
    xout[t] = fmaxf(m, 0.f);
}

// ---------------------------------------------------------------------------
// octree2voxel scatter with transpose: out[b][c][i][j][k] = x3[n][c], r=vox[n]
// ---------------------------------------------------------------------------
__global__ void __launch_bounds__(256) scatter_kernel(
    const float* __restrict__ x3, const int* __restrict__ vox,
    float* __restrict__ out)
{
    const int t = blockIdx.x * 256 + threadIdx.x;  // 1024*64 threads
    const int n = t >> 6, c = t & 63;
    const int r = vox[n];
    out[((r >> 9) << 15) + (c << 9) + (r & 511)] = x3[t];
}

extern "C" void kernel_launch(void* const* d_in, const int* in_sizes, int n_in,
                              void* d_out, int out_size, void* d_ws, size_t ws_size,
                              hipStream_t stream)
{
    const float* data = (const float*)d_in[0];
    const float* W0   = (const float*)d_in[1];
    const float* g0   = (const float*)d_in[2];
    const float* b0   = (const float*)d_in[3];
    const float* W1   = (const float*)d_in[4];
    const float* g1   = (const float*)d_in[5];
    const float* b1   = (const float*)d_in[6];
    const float* W2   = (const float*)d_in[7];
    const float* g2   = (const float*)d_in[8];
    const float* b2   = (const float*)d_in[9];
    const int* neigh0 = (const int*)d_in[10];
    const int* neigh1 = (const int*)d_in[11];
    const int* neigh2 = (const int*)d_in[12];
    const int* vox    = (const int*)d_in[13];

    const int N6 = 524288, N5 = 65536, N4 = 8192, N3 = 1024;

    float* ws = (float*)d_ws;
    const size_t off_y0  = 0;
    const size_t off_x1  = off_y0 + (size_t)N6 * 16;
    const size_t off_y1  = off_x1 + (size_t)N5 * 16;
    const size_t off_x2  = off_y1 + (size_t)N5 * 32;
    const size_t off_y2  = off_x2 + (size_t)N4 * 32;
    const size_t off_x3  = off_y2 + (size_t)N4 * 64;
    const size_t off_st0 = off_x3 + (size_t)N3 * 64;
    const size_t off_st1 = off_st0 + NBUF * 2 * 16;
    const size_t off_st2 = off_st1 + NBUF * 2 * 32;
    const size_t off_ss0 = off_st2 + NBUF * 2 * 64;
    const size_t off_ss1 = off_ss0 + 32;
    const size_t off_ss2 = off_ss1 + 64;

    // zero the stat accumulators every call (graph-replay safe)
    (void)hipMemsetAsync(ws + off_st0, 0, (size_t)(NBUF * 2 * (16 + 32 + 64)) * sizeof(float), stream);

    // stage 0: N6 nodes, Cin 4 -> Cout 16
    conv_kernel<4, 16, 16><<<dim3(N6 / 256, 1), 256, 0, stream>>>(
        data, neigh0, W0, ws + off_y0, ws + off_st0);
    finalize_kernel<<<1, 64, 0, stream>>>(ws + off_st0, g0, b0, ws + off_ss0, 16, 1.f / N6);
    pool_kernel<16><<<(N5 * 16) / 256, 256, 0, stream>>>(ws + off_y0, ws + off_ss0, ws + off_x1, N5 * 16);

    // stage 1: N5 nodes, Cin 16 -> Cout 32
    conv_kernel<16, 32, 32><<<dim3(N5 / 256, 1), 256, 0, stream>>>(
        ws + off_x1, neigh1, W1, ws + off_y1, ws + off_st1);
    finalize_kernel<<<1, 64, 0, stream>>>(ws + off_st1, g1, b1, ws + off_ss1, 32, 1.f / N5);
    pool_kernel<32><<<(N4 * 32) / 256, 256, 0, stream>>>(ws + off_y1, ws + off_ss1, ws + off_x2, N4 * 32);

    // stage 2: N4 nodes, Cin 32 -> Cout 64 (W2 = 221 KB > LDS, tile Cout by 16)
    conv_kernel<32, 16, 64><<<dim3(N4 / 256, 4), 256, 0, stream>>>(
        ws + off_x2, neigh2, W2, ws + off_y2, ws + off_st2);
    finalize_kernel<<<1, 64, 0, stream>>>(ws + off_st2, g2, b2, ws + off_ss2, 64, 1.f / N4);
    pool_kernel<64><<<(N3 * 64) / 256, 256, 0, stream>>>(ws + off_y2, ws + off_ss2, ws + off_x3, N3 * 64);

    // octree2voxel
    (void)hipMemsetAsync(d_out, 0, (size_t)out_size * sizeof(float), stream);
    scatter_kernel<<<(N3 * 64) / 256, 256, 0, stream>>>(ws + off_x3, vox, (float*)d_out);
}

// Round 3
// 370.295 us; speedup vs baseline: 1.5606x; 1.5606x over previous
//
#include <hip/hip_runtime.h>

#define BN_EPS 1e-5f
#define NBUF 64   // spread buffers for stat atomics

// ---------------------------------------------------------------------------
// Stage 0: Cin=4, Cout=16, thread-per-node. Preload 27 idx, gather in groups
// of 9 independent float4 loads -> ~27-deep MLP per thread.
// ---------------------------------------------------------------------------
__global__ void __launch_bounds__(256) conv0_kernel(
    const float* __restrict__ x, const int* __restrict__ neigh,
    const float* __restrict__ W, float* __restrict__ y,
    float* __restrict__ stats)
{
    __shared__ float Wlds[27 * 4 * 16];
    for (int i = threadIdx.x; i < 27 * 4 * 16; i += 256) Wlds[i] = W[i];
    __syncthreads();

    const int node = blockIdx.x * 256 + threadIdx.x;
    const int* nrow = neigh + (size_t)node * 27;

    int idx[27];
#pragma unroll
    for (int j = 0; j < 27; ++j) idx[j] = nrow[j];

    float acc[16];
#pragma unroll
    for (int c = 0; c < 16; ++c) acc[c] = 0.f;

#pragma unroll
    for (int g = 0; g < 27; g += 9) {
        float4 xr[9];
#pragma unroll
        for (int u = 0; u < 9; ++u)
            xr[u] = *(const float4*)(x + (size_t)idx[g + u] * 4);
#pragma unroll
        for (int u = 0; u < 9; ++u) {
            const int j = g + u;
#pragma unroll
            for (int kk = 0; kk < 4; ++kk) {
                const float xv = (kk == 0) ? xr[u].x : (kk == 1) ? xr[u].y
                               : (kk == 2) ? xr[u].z : xr[u].w;
                const float4* wv = (const float4*)&Wlds[(j * 4 + kk) * 16];
#pragma unroll
                for (int c4 = 0; c4 < 4; ++c4) {
                    const float4 w = wv[c4];
                    acc[c4 * 4 + 0] = fmaf(xv, w.x, acc[c4 * 4 + 0]);
                    acc[c4 * 4 + 1] = fmaf(xv, w.y, acc[c4 * 4 + 1]);
                    acc[c4 * 4 + 2] = fmaf(xv, w.z, acc[c4 * 4 + 2]);
                    acc[c4 * 4 + 3] = fmaf(xv, w.w, acc[c4 * 4 + 3]);
                }
            }
        }
    }

    float4* yr = (float4*)(y + (size_t)node * 16);
#pragma unroll
    for (int c4 = 0; c4 < 4; ++c4)
        yr[c4] = make_float4(acc[c4 * 4 + 0], acc[c4 * 4 + 1], acc[c4 * 4 + 2], acc[c4 * 4 + 3]);

    float* buf = stats + (blockIdx.x & (NBUF - 1)) * (2 * 16);
#pragma unroll
    for (int c = 0; c < 16; ++c) {
        float v = acc[c];
        float q = v * v;
#pragma unroll
        for (int off = 32; off > 0; off >>= 1) {
            v += __shfl_xor(v, off, 64);
            q += __shfl_xor(q, off, 64);
        }
        if ((threadIdx.x & 63) == 0) {
            atomicAdd(&buf[c], v);
            atomicAdd(&buf[16 + c], q);
        }
    }
}

// ---------------------------------------------------------------------------
// Generic gather-GEMM (used for stage 1): idx preload + GRP-deep staging.
// ---------------------------------------------------------------------------
template<int CIN, int COUT_TILE, int COUT_TOTAL, int GRP>
__global__ void __launch_bounds__(256) conv_kernel(
    const float* __restrict__ x, const int* __restrict__ neigh,
    const float* __restrict__ W, float* __restrict__ y,
    float* __restrict__ stats)
{
    __shared__ float Wlds[27 * CIN * COUT_TILE];
    const int cobase = blockIdx.y * COUT_TILE;

    for (int i = threadIdx.x; i < 27 * CIN * COUT_TILE; i += 256) {
        int k = i / COUT_TILE, c = i - k * COUT_TILE;
        Wlds[i] = W[k * COUT_TOTAL + cobase + c];
    }
    __syncthreads();

    const int node = blockIdx.x * 256 + threadIdx.x;
    const int* nrow = neigh + (size_t)node * 27;

    int idx[27];
#pragma unroll
    for (int j = 0; j < 27; ++j) idx[j] = nrow[j];

    float acc[COUT_TILE];
#pragma unroll
    for (int c = 0; c < COUT_TILE; ++c) acc[c] = 0.f;

#pragma unroll 1
    for (int g = 0; g < 27; g += GRP) {
        float4 xr[GRP][CIN / 4];
#pragma unroll
        for (int u = 0; u < GRP; ++u) {
            const float4* p = (const float4*)(x + (size_t)idx[g + u] * CIN);
#pragma unroll
            for (int q = 0; q < CIN / 4; ++q) xr[u][q] = p[q];
        }
#pragma unroll
        for (int u = 0; u < GRP; ++u) {
            const int j = g + u;
#pragma unroll
            for (int k4 = 0; k4 < CIN / 4; ++k4) {
                const float4 xq = xr[u][k4];
#pragma unroll
                for (int kk = 0; kk < 4; ++kk) {
                    const float xv = (kk == 0) ? xq.x : (kk == 1) ? xq.y
                                   : (kk == 2) ? xq.z : xq.w;
                    const float4* wv = (const float4*)&Wlds[(j * CIN + k4 * 4 + kk) * COUT_TILE];
#pragma unroll
                    for (int c4 = 0; c4 < COUT_TILE / 4; ++c4) {
                        const float4 w = wv[c4];
                        acc[c4 * 4 + 0] = fmaf(xv, w.x, acc[c4 * 4 + 0]);
                        acc[c4 * 4 + 1] = fmaf(xv, w.y, acc[c4 * 4 + 1]);
                        acc[c4 * 4 + 2] = fmaf(xv, w.z, acc[c4 * 4 + 2]);
                        acc[c4 * 4 + 3] = fmaf(xv, w.w, acc[c4 * 4 + 3]);
                    }
                }
            }
        }
    }

    float4* yr = (float4*)(y + (size_t)node * COUT_TOTAL + cobase);
#pragma unroll
    for (int c4 = 0; c4 < COUT_TILE / 4; ++c4)
        yr[c4] = make_float4(acc[c4 * 4 + 0], acc[c4 * 4 + 1], acc[c4 * 4 + 2], acc[c4 * 4 + 3]);

    float* buf = stats + (blockIdx.x & (NBUF - 1)) * (2 * COUT_TOTAL);
#pragma unroll
    for (int c = 0; c < COUT_TILE; ++c) {
        float v = acc[c];
        float q = v * v;
#pragma unroll
        for (int off = 32; off > 0; off >>= 1) {
            v += __shfl_xor(v, off, 64);
            q += __shfl_xor(q, off, 64);
        }
        if ((threadIdx.x & 63) == 0) {
            atomicAdd(&buf[cobase + c], v);
            atomicAdd(&buf[COUT_TOTAL + cobase + c], q);
        }
    }
}

// ---------------------------------------------------------------------------
// Stage 2: Cin=32, Cout=64. thread-per-(node, channel-quad): 16 nodes/block,
// idx staged in LDS, W read from global (L2-resident, coalesced + broadcast).
// Grid: N4/16 = 512 blocks.
// ---------------------------------------------------------------------------
__global__ void __launch_bounds__(256) conv2_kernel(
    const float* __restrict__ x, const int* __restrict__ neigh,
    const float* __restrict__ W, float* __restrict__ y,
    float* __restrict__ stats)
{
    __shared__ int idxlds[16 * 27];
    const int nbase = blockIdx.x * 16;
    for (int i = threadIdx.x; i < 16 * 27; i += 256) {
        int n = i / 27, j = i - n * 27;
        idxlds[i] = neigh[(size_t)(nbase + n) * 27 + j];
    }
    __syncthreads();

    const int ln = threadIdx.x >> 4;   // local node 0..15
    const int c4 = threadIdx.x & 15;   // channel quad 0..15 (c = c4*4..c4*4+3)
    const int node = nbase + ln;

    float4 acc = make_float4(0.f, 0.f, 0.f, 0.f);

#pragma unroll 1
    for (int j = 0; j < 27; ++j) {
        const int nb = idxlds[ln * 27 + j];
        const float4* xr = (const float4*)(x + (size_t)nb * 32);
        float4 xq[8];
#pragma unroll
        for (int q = 0; q < 8; ++q) xq[q] = xr[q];
#pragma unroll
        for (int q = 0; q < 8; ++q) {
#pragma unroll
            for (int kk = 0; kk < 4; ++kk) {
                const float xv = (kk == 0) ? xq[q].x : (kk == 1) ? xq[q].y
                               : (kk == 2) ? xq[q].z : xq[q].w;
                const int k = q * 4 + kk;
                const float4 w = *(const float4*)(W + ((size_t)j * 32 + k) * 64 + c4 * 4);
                acc.x = fmaf(xv, w.x, acc.x);
                acc.y = fmaf(xv, w.y, acc.y);
                acc.z = fmaf(xv, w.z, acc.z);
                acc.w = fmaf(xv, w.w, acc.w);
            }
        }
    }

    *(float4*)(y + (size_t)node * 64 + c4 * 4) = acc;

    // stats: lanes {c4, c4+16, c4+32, c4+48} hold the same 4 channels
    float sx = acc.x, sy = acc.y, sz = acc.z, sw = acc.w;
    float qx = acc.x * acc.x, qy = acc.y * acc.y, qz = acc.z * acc.z, qw = acc.w * acc.w;
#pragma unroll
    for (int off = 16; off <= 32; off <<= 1) {
        sx += __shfl_xor(sx, off, 64);  sy += __shfl_xor(sy, off, 64);
        sz += __shfl_xor(sz, off, 64);  sw += __shfl_xor(sw, off, 64);
        qx += __shfl_xor(qx, off, 64);  qy += __shfl_xor(qy, off, 64);
        qz += __shfl_xor(qz, off, 64);  qw += __shfl_xor(qw, off, 64);
    }
    if ((threadIdx.x & 63) < 16) {
        float* buf = stats + (blockIdx.x & (NBUF - 1)) * (2 * 64);
        atomicAdd(&buf[c4 * 4 + 0], sx);
        atomicAdd(&buf[c4 * 4 + 1], sy);
        atomicAdd(&buf[c4 * 4 + 2], sz);
        atomicAdd(&buf[c4 * 4 + 3], sw);
        atomicAdd(&buf[64 + c4 * 4 + 0], qx);
        atomicAdd(&buf[64 + c4 * 4 + 1], qy);
        atomicAdd(&buf[64 + c4 * 4 + 2], qz);
        atomicAdd(&buf[64 + c4 * 4 + 3], qw);
    }
}

// ---------------------------------------------------------------------------
__global__ void finalize_kernel(const float* __restrict__ stats,
                                const float* __restrict__ gamma,
                                const float* __restrict__ beta,
                                float* __restrict__ ss, int COUT, float invN)
{
    const int c = threadIdx.x;
    if (c >= COUT) return;
    float s = 0.f, q = 0.f;
    for (int b = 0; b < NBUF; ++b) {
        s += stats[b * 2 * COUT + c];
        q += stats[b * 2 * COUT + COUT + c];
    }
    const float mean = s * invN;
    const float var  = fmaf(-mean, mean, q * invN);
    const float sc   = gamma[c] * rsqrtf(var + BN_EPS);
    ss[c]        = sc;
    ss[COUT + c] = fmaf(-mean, sc, beta[c]);
}

// ---------------------------------------------------------------------------
template<int COUT>
__global__ void __launch_bounds__(256) pool_kernel(
    const float* __restrict__ y, const float* __restrict__ ss,
    float* __restrict__ xout, int total)
{
    const int t = blockIdx.x * 256 + threadIdx.x;
    if (t >= total) return;
    const int p = t / COUT, c = t % COUT;
    const float sc = ss[c], sh = ss[COUT + c];
    const float* yr = y + (size_t)p * 8 * COUT + c;
    float m = -3.4e38f;
#pragma unroll
    for (int i = 0; i < 8; ++i) m = fmaxf(m, fmaf(yr[i * COUT], sc, sh));
    xout[t] = fmaxf(m, 0.f);
}

// ---------------------------------------------------------------------------
__global__ void __launch_bounds__(256) scatter_kernel(
    const float* __restrict__ x3, const int* __restrict__ vox,
    float* __restrict__ out)
{
    const int t = blockIdx.x * 256 + threadIdx.x;  // 1024*64 threads
    const int n = t >> 6, c = t & 63;
    const int r = vox[n];
    out[((r >> 9) << 15) + (c << 9) + (r & 511)] = x3[t];
}

extern "C" void kernel_launch(void* const* d_in, const int* in_sizes, int n_in,
                              void* d_out, int out_size, void* d_ws, size_t ws_size,
                              hipStream_t stream)
{
    const float* data = (const float*)d_in[0];
    const float* W0   = (const float*)d_in[1];
    const float* g0   = (const float*)d_in[2];
    const float* b0   = (const float*)d_in[3];
    const float* W1   = (const float*)d_in[4];
    const float* g1   = (const float*)d_in[5];
    const float* b1   = (const float*)d_in[6];
    const float* W2   = (const float*)d_in[7];
    const float* g2   = (const float*)d_in[8];
    const float* b2   = (const float*)d_in[9];
    const int* neigh0 = (const int*)d_in[10];
    const int* neigh1 = (const int*)d_in[11];
    const int* neigh2 = (const int*)d_in[12];
    const int* vox    = (const int*)d_in[13];

    const int N6 = 524288, N5 = 65536, N4 = 8192, N3 = 1024;

    float* ws = (float*)d_ws;
    const size_t off_y0  = 0;
    const size_t off_x1  = off_y0 + (size_t)N6 * 16;
    const size_t off_y1  = off_x1 + (size_t)N5 * 16;
    const size_t off_x2  = off_y1 + (size_t)N5 * 32;
    const size_t off_y2  = off_x2 + (size_t)N4 * 32;
    const size_t off_x3  = off_y2 + (size_t)N4 * 64;
    const size_t off_st0 = off_x3 + (size_t)N3 * 64;
    const size_t off_st1 = off_st0 + NBUF * 2 * 16;
    const size_t off_st2 = off_st1 + NBUF * 2 * 32;
    const size_t off_ss0 = off_st2 + NBUF * 2 * 64;
    const size_t off_ss1 = off_ss0 + 32;
    const size_t off_ss2 = off_ss1 + 64;

    (void)hipMemsetAsync(ws + off_st0, 0, (size_t)(NBUF * 2 * (16 + 32 + 64)) * sizeof(float), stream);

    // stage 0: N6 nodes, 4 -> 16
    conv0_kernel<<<N6 / 256, 256, 0, stream>>>(data, neigh0, W0, ws + off_y0, ws + off_st0);
    finalize_kernel<<<1, 64, 0, stream>>>(ws + off_st0, g0, b0, ws + off_ss0, 16, 1.f / N6);
    pool_kernel<16><<<(N5 * 16) / 256, 256, 0, stream>>>(ws + off_y0, ws + off_ss0, ws + off_x1, N5 * 16);

    // stage 1: N5 nodes, 16 -> 32 (Cout tiled by 8 for occupancy)
    conv_kernel<16, 8, 32, 3><<<dim3(N5 / 256, 4), 256, 0, stream>>>(
        ws + off_x1, neigh1, W1, ws + off_y1, ws + off_st1);
    finalize_kernel<<<1, 64, 0, stream>>>(ws + off_st1, g1, b1, ws + off_ss1, 32, 1.f / N5);
    pool_kernel<32><<<(N4 * 32) / 256, 256, 0, stream>>>(ws + off_y1, ws + off_ss1, ws + off_x2, N4 * 32);

    // stage 2: N4 nodes, 32 -> 64, thread-per-(node, channel-quad)
    conv2_kernel<<<N4 / 16, 256, 0, stream>>>(ws + off_x2, neigh2, W2, ws + off_y2, ws + off_st2);
    finalize_kernel<<<1, 64, 0, stream>>>(ws + off_st2, g2, b2, ws + off_ss2, 64, 1.f / N4);
    pool_kernel<64><<<(N3 * 64) / 256, 256, 0, stream>>>(ws + off_y2, ws + off_ss2, ws + off_x3, N3 * 64);

    // octree2voxel
    (void)hipMemsetAsync(d_out, 0, (size_t)out_size * sizeof(float), stream);
    scatter_kernel<<<(N3 * 64) / 256, 256, 0, stream>>>(ws + off_x3, vox, (float*)d_out);
}

// Round 4
// 280.609 us; speedup vs baseline: 2.0594x; 1.3196x over previous
//
#include <hip/hip_runtime.h>

#define BN_EPS 1e-5f
#define NBUF 64   // spread buffers for stat atomics

typedef float        f32x4 __attribute__((ext_vector_type(4)));
typedef float        f32x2 __attribute__((ext_vector_type(2)));
typedef unsigned int u32x2 __attribute__((ext_vector_type(2)));
typedef unsigned int u32x4 __attribute__((ext_vector_type(4)));

__device__ inline unsigned pack_bf16(float a, float b) {
    unsigned ua = __float_as_uint(a);
    unsigned ub = __float_as_uint(b);
    ua = (ua + 0x7fffu + ((ua >> 16) & 1u)) >> 16;
    ub = (ub + 0x7fffu + ((ub >> 16) & 1u)) >> 16;
    return ua | (ub << 16);
}
__device__ inline float bf_lo(unsigned u) { return __uint_as_float(u << 16); }
__device__ inline float bf_hi(unsigned u) { return __uint_as_float(u & 0xffff0000u); }

// ---------------------------------------------------------------------------
// Cast fp32 -> packed bf16 (RNE). One thread = 4 floats -> 2 uints.
// ---------------------------------------------------------------------------
__global__ void __launch_bounds__(256) cast_bf16_kernel(
    const f32x4* __restrict__ in, u32x2* __restrict__ out, int n4)
{
    const int t = blockIdx.x * 256 + threadIdx.x;
    if (t >= n4) return;
    const f32x4 v = in[t];
    u32x2 r;
    r.x = pack_bf16(v.x, v.y);
    r.y = pack_bf16(v.z, v.w);
    out[t] = r;
}

// ---------------------------------------------------------------------------
// Stage 0: Cin=4 (bf16, 8B rows -> 4MB table, L2-resident), Cout=16.
// Thread-per-node, 27 idx preload (NT), gathers in groups of 9.
// ---------------------------------------------------------------------------
__global__ void __launch_bounds__(256) conv0_kernel(
    const u32x2* __restrict__ xb, const int* __restrict__ neigh,
    const float* __restrict__ W, float* __restrict__ y,
    float* __restrict__ stats)
{
    __shared__ float Wlds[27 * 4 * 16];
    for (int i = threadIdx.x; i < 27 * 4 * 16; i += 256) Wlds[i] = W[i];
    __syncthreads();

    const int node = blockIdx.x * 256 + threadIdx.x;
    const int* nrow = neigh + (size_t)node * 27;

    int idx[27];
#pragma unroll
    for (int j = 0; j < 27; ++j) idx[j] = __builtin_nontemporal_load(nrow + j);

    float acc[16];
#pragma unroll
    for (int c = 0; c < 16; ++c) acc[c] = 0.f;

#pragma unroll
    for (int g = 0; g < 27; g += 9) {
        u32x2 xr[9];
#pragma unroll
        for (int u = 0; u < 9; ++u) xr[u] = xb[idx[g + u]];
#pragma unroll
        for (int u = 0; u < 9; ++u) {
            const int j = g + u;
            float xv[4];
            xv[0] = bf_lo(xr[u].x); xv[1] = bf_hi(xr[u].x);
            xv[2] = bf_lo(xr[u].y); xv[3] = bf_hi(xr[u].y);
#pragma unroll
            for (int kk = 0; kk < 4; ++kk) {
                const f32x4* wv = (const f32x4*)&Wlds[(j * 4 + kk) * 16];
#pragma unroll
                for (int c4 = 0; c4 < 4; ++c4) {
                    const f32x4 w = wv[c4];
                    acc[c4 * 4 + 0] = fmaf(xv[kk], w.x, acc[c4 * 4 + 0]);
                    acc[c4 * 4 + 1] = fmaf(xv[kk], w.y, acc[c4 * 4 + 1]);
                    acc[c4 * 4 + 2] = fmaf(xv[kk], w.z, acc[c4 * 4 + 2]);
                    acc[c4 * 4 + 3] = fmaf(xv[kk], w.w, acc[c4 * 4 + 3]);
                }
            }
        }
    }

    f32x4* yr = (f32x4*)(y + (size_t)node * 16);
#pragma unroll
    for (int c4 = 0; c4 < 4; ++c4) {
        f32x4 v = { acc[c4 * 4 + 0], acc[c4 * 4 + 1], acc[c4 * 4 + 2], acc[c4 * 4 + 3] };
        __builtin_nontemporal_store(v, yr + c4);
    }

    float* buf = stats + (blockIdx.x & (NBUF - 1)) * (2 * 16);
#pragma unroll
    for (int c = 0; c < 16; ++c) {
        float v = acc[c];
        float q = v * v;
#pragma unroll
        for (int off = 32; off > 0; off >>= 1) {
            v += __shfl_xor(v, off, 64);
            q += __shfl_xor(q, off, 64);
        }
        if ((threadIdx.x & 63) == 0) {
            atomicAdd(&buf[c], v);
            atomicAdd(&buf[16 + c], q);
        }
    }
}

// ---------------------------------------------------------------------------
// Stage 1: Cin=16 (bf16, 32B rows -> 2MB table), Cout=32 tiled by 16.
// Grid (N5/256, 2). LDS W tile 27.6KB.
// ---------------------------------------------------------------------------
__global__ void __launch_bounds__(256) conv1_kernel(
    const u32x4* __restrict__ xb, const int* __restrict__ neigh,
    const float* __restrict__ W, float* __restrict__ y,
    float* __restrict__ stats)
{
    __shared__ float Wlds[27 * 16 * 16];
    const int cobase = blockIdx.y * 16;

    for (int i = threadIdx.x; i < 27 * 16 * 16; i += 256) {
        int k = i >> 4, c = i & 15;
        Wlds[i] = W[k * 32 + cobase + c];
    }
    __syncthreads();

    const int node = blockIdx.x * 256 + threadIdx.x;
    const int* nrow = neigh + (size_t)node * 27;

    int idx[27];
#pragma unroll
    for (int j = 0; j < 27; ++j) idx[j] = __builtin_nontemporal_load(nrow + j);

    float acc[16];
#pragma unroll
    for (int c = 0; c < 16; ++c) acc[c] = 0.f;

#pragma unroll 1
    for (int g = 0; g < 27; g += 3) {
        u32x4 xa[3], xc[3];
#pragma unroll
        for (int u = 0; u < 3; ++u) {
            const size_t r = (size_t)idx[g + u] * 2;
            xa[u] = xb[r];
            xc[u] = xb[r + 1];
        }
#pragma unroll
        for (int u = 0; u < 3; ++u) {
            const int j = g + u;
            float xv[16];
            xv[0]  = bf_lo(xa[u].x); xv[1]  = bf_hi(xa[u].x);
            xv[2]  = bf_lo(xa[u].y); xv[3]  = bf_hi(xa[u].y);
            xv[4]  = bf_lo(xa[u].z); xv[5]  = bf_hi(xa[u].z);
            xv[6]  = bf_lo(xa[u].w); xv[7]  = bf_hi(xa[u].w);
            xv[8]  = bf_lo(xc[u].x); xv[9]  = bf_hi(xc[u].x);
            xv[10] = bf_lo(xc[u].y); xv[11] = bf_hi(xc[u].y);
            xv[12] = bf_lo(xc[u].z); xv[13] = bf_hi(xc[u].z);
            xv[14] = bf_lo(xc[u].w); xv[15] = bf_hi(xc[u].w);
#pragma unroll
            for (int k = 0; k < 16; ++k) {
                const f32x4* wv = (const f32x4*)&Wlds[(j * 16 + k) * 16];
#pragma unroll
                for (int c4 = 0; c4 < 4; ++c4) {
                    const f32x4 w = wv[c4];
                    acc[c4 * 4 + 0] = fmaf(xv[k], w.x, acc[c4 * 4 + 0]);
                    acc[c4 * 4 + 1] = fmaf(xv[k], w.y, acc[c4 * 4 + 1]);
                    acc[c4 * 4 + 2] = fmaf(xv[k], w.z, acc[c4 * 4 + 2]);
                    acc[c4 * 4 + 3] = fmaf(xv[k], w.w, acc[c4 * 4 + 3]);
                }
            }
        }
    }

    f32x4* yr = (f32x4*)(y + (size_t)node * 32 + cobase);
#pragma unroll
    for (int c4 = 0; c4 < 4; ++c4) {
        f32x4 v = { acc[c4 * 4 + 0], acc[c4 * 4 + 1], acc[c4 * 4 + 2], acc[c4 * 4 + 3] };
        __builtin_nontemporal_store(v, yr + c4);
    }

    float* buf = stats + (blockIdx.x & (NBUF - 1)) * (2 * 32);
#pragma unroll
    for (int c = 0; c < 16; ++c) {
        float v = acc[c];
        float q = v * v;
#pragma unroll
        for (int off = 32; off > 0; off >>= 1) {
            v += __shfl_xor(v, off, 64);
            q += __shfl_xor(q, off, 64);
        }
        if ((threadIdx.x & 63) == 0) {
            atomicAdd(&buf[cobase + c], v);
            atomicAdd(&buf[32 + cobase + c], q);
        }
    }
}

// ---------------------------------------------------------------------------
// Stage 2: Cin=32 (bf16, 64B rows), Cout=64. thread-per-(node, channel-quad),
// 16 nodes/block, idx in LDS, W fp32 straight from L2 (coalesced+reused).
// ---------------------------------------------------------------------------
__global__ void __launch_bounds__(256) conv2_kernel(
    const u32x4* __restrict__ xb, const int* __restrict__ neigh,
    const float* __restrict__ W, float* __restrict__ y,
    float* __restrict__ stats)
{
    __shared__ int idxlds[16 * 27];
    const int nbase = blockIdx.x * 16;
    for (int i = threadIdx.x; i < 16 * 27; i += 256) {
        int n = i / 27, j = i - n * 27;
        idxlds[i] = __builtin_nontemporal_load(neigh + (size_t)(nbase + n) * 27 + j);
    }
    __syncthreads();

    const int ln = threadIdx.x >> 4;
    const int c4 = threadIdx.x & 15;
    const int node = nbase + ln;

    f32x4 acc = { 0.f, 0.f, 0.f, 0.f };

#pragma unroll 1
    for (int j = 0; j < 27; ++j) {
        const int nb = idxlds[ln * 27 + j];
        const u32x4* xr = xb + (size_t)nb * 4;
        u32x4 xq[4];
#pragma unroll
        for (int q = 0; q < 4; ++q) xq[q] = xr[q];
#pragma unroll
        for (int q = 0; q < 4; ++q) {
            float xv[8];
            xv[0] = bf_lo(xq[q].x); xv[1] = bf_hi(xq[q].x);
            xv[2] = bf_lo(xq[q].y); xv[3] = bf_hi(xq[q].y);
            xv[4] = bf_lo(xq[q].z); xv[5] = bf_hi(xq[q].z);
            xv[6] = bf_lo(xq[q].w); xv[7] = bf_hi(xq[q].w);
#pragma unroll
            for (int h = 0; h < 8; ++h) {
                const int k = q * 8 + h;
                const f32x4 w = *(const f32x4*)(W + ((size_t)j * 32 + k) * 64 + c4 * 4);
                acc.x = fmaf(xv[h], w.x, acc.x);
                acc.y = fmaf(xv[h], w.y, acc.y);
                acc.z = fmaf(xv[h], w.z, acc.z);
                acc.w = fmaf(xv[h], w.w, acc.w);
            }
        }
    }

    __builtin_nontemporal_store(acc, (f32x4*)(y + (size_t)node * 64 + c4 * 4));

    float sx = acc.x, sy = acc.y, sz = acc.z, sw = acc.w;
    float qx = acc.x * acc.x, qy = acc.y * acc.y, qz = acc.z * acc.z, qw = acc.w * acc.w;
#pragma unroll
    for (int off = 16; off <= 32; off <<= 1) {
        sx += __shfl_xor(sx, off, 64);  sy += __shfl_xor(sy, off, 64);
        sz += __shfl_xor(sz, off, 64);  sw += __shfl_xor(sw, off, 64);
        qx += __shfl_xor(qx, off, 64);  qy += __shfl_xor(qy, off, 64);
        qz += __shfl_xor(qz, off, 64);  qw += __shfl_xor(qw, off, 64);
    }
    if ((threadIdx.x & 63) < 16) {
        float* buf = stats + (blockIdx.x & (NBUF - 1)) * (2 * 64);
        atomicAdd(&buf[c4 * 4 + 0], sx);
        atomicAdd(&buf[c4 * 4 + 1], sy);
        atomicAdd(&buf[c4 * 4 + 2], sz);
        atomicAdd(&buf[c4 * 4 + 3], sw);
        atomicAdd(&buf[64 + c4 * 4 + 0], qx);
        atomicAdd(&buf[64 + c4 * 4 + 1], qy);
        atomicAdd(&buf[64 + c4 * 4 + 2], qz);
        atomicAdd(&buf[64 + c4 * 4 + 3], qw);
    }
}

// ---------------------------------------------------------------------------
// Fused BN-finalize (per-block recompute) + affine + ReLU + 8-sibling maxpool.
// Thread t -> (parent p, channel pair c2). BF16OUT packs pairs into uint.
// ---------------------------------------------------------------------------
template<int COUT, bool BF16OUT>
__global__ void __launch_bounds__(256) pool_fin_kernel(
    const float* __restrict__ y, const float* __restrict__ stats,
    const float* __restrict__ gamma, const float* __restrict__ beta,
    void* __restrict__ xout, float invN, int total2)
{
    __shared__ float ss[2 * COUT];
    if (threadIdx.x < COUT) {
        const int c = threadIdx.x;
        float s = 0.f, q = 0.f;
        for (int b = 0; b < NBUF; ++b) {
            s += stats[b * 2 * COUT + c];
            q += stats[b * 2 * COUT + COUT + c];
        }
        const float mean = s * invN;
        const float var  = fmaf(-mean, mean, q * invN);
        const float sc   = gamma[c] * rsqrtf(var + BN_EPS);
        ss[c]        = sc;
        ss[COUT + c] = fmaf(-mean, sc, beta[c]);
    }
    __syncthreads();

    const int t = blockIdx.x * 256 + threadIdx.x;
    if (t >= total2) return;
    const int p  = t / (COUT / 2);
    const int c2 = (t % (COUT / 2)) * 2;
    const float sc0 = ss[c2],     sh0 = ss[COUT + c2];
    const float sc1 = ss[c2 + 1], sh1 = ss[COUT + c2 + 1];
    const float* yr = y + (size_t)p * 8 * COUT + c2;
    float m0 = -3.4e38f, m1 = -3.4e38f;
#pragma unroll
    for (int i = 0; i < 8; ++i) {
        const f32x2 v = __builtin_nontemporal_load((const f32x2*)(yr + i * COUT));
        m0 = fmaxf(m0, fmaf(v.x, sc0, sh0));
        m1 = fmaxf(m1, fmaf(v.y, sc1, sh1));
    }
    m0 = fmaxf(m0, 0.f);
    m1 = fmaxf(m1, 0.f);
    if (BF16OUT) {
        ((unsigned*)xout)[t] = pack_bf16(m0, m1);
    } else {
        f32x2 r = { m0, m1 };
        ((f32x2*)xout)[t] = r;
    }
}

// ---------------------------------------------------------------------------
// octree2voxel scatter with transpose: out[b][c][i][j][k] = x3[n][c], r=vox[n]
// ---------------------------------------------------------------------------
__global__ void __launch_bounds__(256) scatter_kernel(
    const float* __restrict__ x3, const int* __restrict__ vox,
    float* __restrict__ out)
{
    const int t = blockIdx.x * 256 + threadIdx.x;  // 1024*64 threads
    const int n = t >> 6, c = t & 63;
    const int r = vox[n];
    out[((r >> 9) << 15) + (c << 9) + (r & 511)] = x3[t];
}

extern "C" void kernel_launch(void* const* d_in, const int* in_sizes, int n_in,
                              void* d_out, int out_size, void* d_ws, size_t ws_size,
                              hipStream_t stream)
{
    const float* data = (const float*)d_in[0];
    const float* W0   = (const float*)d_in[1];
    const float* g0   = (const float*)d_in[2];
    const float* b0   = (const float*)d_in[3];
    const float* W1   = (const float*)d_in[4];
    const float* g1   = (const float*)d_in[5];
    const float* b1   = (const float*)d_in[6];
    const float* W2   = (const float*)d_in[7];
    const float* g2   = (const float*)d_in[8];
    const float* b2   = (const float*)d_in[9];
    const int* neigh0 = (const int*)d_in[10];
    const int* neigh1 = (const int*)d_in[11];
    const int* neigh2 = (const int*)d_in[12];
    const int* vox    = (const int*)d_in[13];

    const int N6 = 524288, N5 = 65536, N4 = 8192, N3 = 1024;

    float* ws = (float*)d_ws;
    // layout (floats). xb0 is aliased into the y1 region (y1 written only
    // after conv0 has consumed xb0).
    const size_t off_y0  = 0;                                 // N6*16
    const size_t off_xb1 = off_y0 + (size_t)N6 * 16;          // N5*8  (bf16 x1)
    const size_t off_y1  = off_xb1 + (size_t)N5 * 8;          // N5*32
    const size_t off_xb0 = off_y1;                            // N6*2  (bf16 x0, alias)
    const size_t off_xb2 = off_y1 + (size_t)N5 * 32;          // N4*16 (bf16 x2)
    const size_t off_y2  = off_xb2 + (size_t)N4 * 16;         // N4*64
    const size_t off_x3  = off_y2 + (size_t)N4 * 64;          // N3*64
    const size_t off_st0 = off_x3 + (size_t)N3 * 64;          // NBUF*2*16
    const size_t off_st1 = off_st0 + NBUF * 2 * 16;           // NBUF*2*32
    const size_t off_st2 = off_st1 + NBUF * 2 * 32;           // NBUF*2*64

    (void)hipMemsetAsync(ws + off_st0, 0, (size_t)(NBUF * 2 * (16 + 32 + 64)) * sizeof(float), stream);

    // stage 0: cast data -> bf16 table (4MB, L2-resident), then conv
    cast_bf16_kernel<<<(N6 * 4 / 4) / 256, 256, 0, stream>>>(
        (const f32x4*)data, (u32x2*)(ws + off_xb0), N6);
    conv0_kernel<<<N6 / 256, 256, 0, stream>>>(
        (const u32x2*)(ws + off_xb0), neigh0, W0, ws + off_y0, ws + off_st0);
    pool_fin_kernel<16, true><<<(N5 * 8) / 256, 256, 0, stream>>>(
        ws + off_y0, ws + off_st0, g0, b0, ws + off_xb1, 1.f / N6, N5 * 8);

    // stage 1
    conv1_kernel<<<dim3(N5 / 256, 2), 256, 0, stream>>>(
        (const u32x4*)(ws + off_xb1), neigh1, W1, ws + off_y1, ws + off_st1);
    pool_fin_kernel<32, true><<<(N4 * 16) / 256, 256, 0, stream>>>(
        ws + off_y1, ws + off_st1, g1, b1, ws + off_xb2, 1.f / N5, N4 * 16);

    // stage 2
    conv2_kernel<<<N4 / 16, 256, 0, stream>>>(
        (const u32x4*)(ws + off_xb2), neigh2, W2, ws + off_y2, ws + off_st2);
    pool_fin_kernel<64, false><<<(N3 * 32) / 256, 256, 0, stream>>>(
        ws + off_y2, ws + off_st2, g2, b2, ws + off_x3, 1.f / N4, N3 * 32);

    // octree2voxel
    (void)hipMemsetAsync(d_out, 0, (size_t)out_size * sizeof(float), stream);
    scatter_kernel<<<(N3 * 64) / 256, 256, 0, stream>>>(ws + off_x3, vox, (float*)d_out);
}

// Round 5
// 275.873 us; speedup vs baseline: 2.0948x; 1.0172x over previous
//
#include <hip/hip_runtime.h>

#define BN_EPS 1e-5f
#define NBUF 64   // spread buffers for stat atomics

typedef float        f32x4 __attribute__((ext_vector_type(4)));
typedef float        f32x2 __attribute__((ext_vector_type(2)));
typedef unsigned int u32x2 __attribute__((ext_vector_type(2)));
typedef unsigned int u32x4 __attribute__((ext_vector_type(4)));

__device__ inline unsigned pack_bf16(float a, float b) {
    unsigned ua = __float_as_uint(a);
    unsigned ub = __float_as_uint(b);
    ua = (ua + 0x7fffu + ((ua >> 16) & 1u)) >> 16;
    ub = (ub + 0x7fffu + ((ub >> 16) & 1u)) >> 16;
    return ua | (ub << 16);
}
__device__ inline float bf_lo(unsigned u) { return __uint_as_float(u << 16); }
__device__ inline float bf_hi(unsigned u) { return __uint_as_float(u & 0xffff0000u); }

// ---------------------------------------------------------------------------
// Cast fp32 -> packed bf16 (RNE). One thread = 4 floats -> 2 uints.
// ---------------------------------------------------------------------------
__global__ void __launch_bounds__(256) cast_bf16_kernel(
    const f32x4* __restrict__ in, u32x2* __restrict__ out, int n4)
{
    const int t = blockIdx.x * 256 + threadIdx.x;
    if (t >= n4) return;
    const f32x4 v = in[t];
    u32x2 r;
    r.x = pack_bf16(v.x, v.y);
    r.y = pack_bf16(v.z, v.w);
    out[t] = r;
}

// ---------------------------------------------------------------------------
// Stage 0: Cin=4 (bf16, 8B rows -> 4MB table, L2-resident), Cout=16.
// Gathers are agent-scope relaxed loads -> sc0 -> L1 bypass, straight to L2.
// ---------------------------------------------------------------------------
__global__ void __launch_bounds__(256) conv0_kernel(
    const unsigned long long* __restrict__ xb, const int* __restrict__ neigh,
    const float* __restrict__ W, float* __restrict__ y,
    float* __restrict__ stats)
{
    __shared__ float Wlds[27 * 4 * 16];
    for (int i = threadIdx.x; i < 27 * 4 * 16; i += 256) Wlds[i] = W[i];
    __syncthreads();

    const int node = blockIdx.x * 256 + threadIdx.x;
    const int* nrow = neigh + (size_t)node * 27;

    int idx[27];
#pragma unroll
    for (int j = 0; j < 27; ++j) idx[j] = __builtin_nontemporal_load(nrow + j);

    float acc[16];
#pragma unroll
    for (int c = 0; c < 16; ++c) acc[c] = 0.f;

#pragma unroll
    for (int g = 0; g < 27; g += 9) {
        unsigned long long xr[9];
#pragma unroll
        for (int u = 0; u < 9; ++u)
            xr[u] = __hip_atomic_load(xb + idx[g + u], __ATOMIC_RELAXED,
                                      __HIP_MEMORY_SCOPE_AGENT);
#pragma unroll
        for (int u = 0; u < 9; ++u) {
            const int j = g + u;
            const unsigned lo = (unsigned)xr[u];
            const unsigned hi = (unsigned)(xr[u] >> 32);
            float xv[4];
            xv[0] = bf_lo(lo); xv[1] = bf_hi(lo);
            xv[2] = bf_lo(hi); xv[3] = bf_hi(hi);
#pragma unroll
            for (int kk = 0; kk < 4; ++kk) {
                const f32x4* wv = (const f32x4*)&Wlds[(j * 4 + kk) * 16];
#pragma unroll
                for (int c4 = 0; c4 < 4; ++c4) {
                    const f32x4 w = wv[c4];
                    acc[c4 * 4 + 0] = fmaf(xv[kk], w.x, acc[c4 * 4 + 0]);
                    acc[c4 * 4 + 1] = fmaf(xv[kk], w.y, acc[c4 * 4 + 1]);
                    acc[c4 * 4 + 2] = fmaf(xv[kk], w.z, acc[c4 * 4 + 2]);
                    acc[c4 * 4 + 3] = fmaf(xv[kk], w.w, acc[c4 * 4 + 3]);
                }
            }
        }
    }

    f32x4* yr = (f32x4*)(y + (size_t)node * 16);
#pragma unroll
    for (int c4 = 0; c4 < 4; ++c4) {
        f32x4 v = { acc[c4 * 4 + 0], acc[c4 * 4 + 1], acc[c4 * 4 + 2], acc[c4 * 4 + 3] };
        __builtin_nontemporal_store(v, yr + c4);
    }

    float* buf = stats + (blockIdx.x & (NBUF - 1)) * (2 * 16);
#pragma unroll
    for (int c = 0; c < 16; ++c) {
        float v = acc[c];
        float q = v * v;
#pragma unroll
        for (int off = 32; off > 0; off >>= 1) {
            v += __shfl_xor(v, off, 64);
            q += __shfl_xor(q, off, 64);
        }
        if ((threadIdx.x & 63) == 0) {
            atomicAdd(&buf[c], v);
            atomicAdd(&buf[16 + c], q);
        }
    }
}

// ---------------------------------------------------------------------------
// Stage 1: Cin=16 (bf16, 32B rows -> 2MB table), Cout=32 tiled by 8.
// Grid (N5/256, 4), LDS 13.8KB -> ~4 blocks/CU for latency hiding.
// ---------------------------------------------------------------------------
__global__ void __launch_bounds__(256) conv1_kernel(
    const u32x4* __restrict__ xb, const int* __restrict__ neigh,
    const float* __restrict__ W, float* __restrict__ y,
    float* __restrict__ stats)
{
    __shared__ float Wlds[27 * 16 * 8];
    const int cobase = blockIdx.y * 8;

    for (int i = threadIdx.x; i < 27 * 16 * 8; i += 256) {
        int k = i >> 3, c = i & 7;
        Wlds[i] = W[k * 32 + cobase + c];
    }
    __syncthreads();

    const int node = blockIdx.x * 256 + threadIdx.x;
    const int* nrow = neigh + (size_t)node * 27;

    int idx[27];
#pragma unroll
    for (int j = 0; j < 27; ++j) idx[j] = __builtin_nontemporal_load(nrow + j);

    float acc[8];
#pragma unroll
    for (int c = 0; c < 8; ++c) acc[c] = 0.f;

#pragma unroll 1
    for (int g = 0; g < 27; g += 3) {
        u32x4 xa[3], xc[3];
#pragma unroll
        for (int u = 0; u < 3; ++u) {
            const size_t r = (size_t)idx[g + u] * 2;
            xa[u] = xb[r];
            xc[u] = xb[r + 1];
        }
#pragma unroll
        for (int u = 0; u < 3; ++u) {
            const int j = g + u;
            float xv[16];
            xv[0]  = bf_lo(xa[u].x); xv[1]  = bf_hi(xa[u].x);
            xv[2]  = bf_lo(xa[u].y); xv[3]  = bf_hi(xa[u].y);
            xv[4]  = bf_lo(xa[u].z); xv[5]  = bf_hi(xa[u].z);
            xv[6]  = bf_lo(xa[u].w); xv[7]  = bf_hi(xa[u].w);
            xv[8]  = bf_lo(xc[u].x); xv[9]  = bf_hi(xc[u].x);
            xv[10] = bf_lo(xc[u].y); xv[11] = bf_hi(xc[u].y);
            xv[12] = bf_lo(xc[u].z); xv[13] = bf_hi(xc[u].z);
            xv[14] = bf_lo(xc[u].w); xv[15] = bf_hi(xc[u].w);
#pragma unroll
            for (int k = 0; k < 16; ++k) {
                const f32x4* wv = (const f32x4*)&Wlds[(j * 16 + k) * 8];
#pragma unroll
                for (int c4 = 0; c4 < 2; ++c4) {
                    const f32x4 w = wv[c4];
                    acc[c4 * 4 + 0] = fmaf(xv[k], w.x, acc[c4 * 4 + 0]);
                    acc[c4 * 4 + 1] = fmaf(xv[k], w.y, acc[c4 * 4 + 1]);
                    acc[c4 * 4 + 2] = fmaf(xv[k], w.z, acc[c4 * 4 + 2]);
                    acc[c4 * 4 + 3] = fmaf(xv[k], w.w, acc[c4 * 4 + 3]);
                }
            }
        }
    }

    f32x4* yr = (f32x4*)(y + (size_t)node * 32 + cobase);
#pragma unroll
    for (int c4 = 0; c4 < 2; ++c4) {
        f32x4 v = { acc[c4 * 4 + 0], acc[c4 * 4 + 1], acc[c4 * 4 + 2], acc[c4 * 4 + 3] };
        __builtin_nontemporal_store(v, yr + c4);
    }

    float* buf = stats + (blockIdx.x & (NBUF - 1)) * (2 * 32);
#pragma unroll
    for (int c = 0; c < 8; ++c) {
        float v = acc[c];
        float q = v * v;
#pragma unroll
        for (int off = 32; off > 0; off >>= 1) {
            v += __shfl_xor(v, off, 64);
            q += __shfl_xor(q, off, 64);
        }
        if ((threadIdx.x & 63) == 0) {
            atomicAdd(&buf[cobase + c], v);
            atomicAdd(&buf[32 + cobase + c], q);
        }
    }
}

// ---------------------------------------------------------------------------
// Stage 2: Cin=32 (bf16, 64B rows), Cout=64. thread-per-(node, channel-quad),
// 16 nodes/block, idx in LDS, W fp32 straight from L2 (coalesced+reused).
// ---------------------------------------------------------------------------
__global__ void __launch_bounds__(256) conv2_kernel(
    const u32x4* __restrict__ xb, const int* __restrict__ neigh,
    const float* __restrict__ W, float* __restrict__ y,
    float* __restrict__ stats)
{
    __shared__ int idxlds[16 * 27];
    const int nbase = blockIdx.x * 16;
    for (int i = threadIdx.x; i < 16 * 27; i += 256) {
        int n = i / 27, j = i - n * 27;
        idxlds[i] = __builtin_nontemporal_load(neigh + (size_t)(nbase + n) * 27 + j);
    }
    __syncthreads();

    const int ln = threadIdx.x >> 4;
    const int c4 = threadIdx.x & 15;
    const int node = nbase + ln;

    f32x4 acc = { 0.f, 0.f, 0.f, 0.f };

#pragma unroll 1
    for (int j = 0; j < 27; ++j) {
        const int nb = idxlds[ln * 27 + j];
        const u32x4* xr = xb + (size_t)nb * 4;
        u32x4 xq[4];
#pragma unroll
        for (int q = 0; q < 4; ++q) xq[q] = xr[q];
#pragma unroll
        for (int q = 0; q < 4; ++q) {
            float xv[8];
            xv[0] = bf_lo(xq[q].x); xv[1] = bf_hi(xq[q].x);
            xv[2] = bf_lo(xq[q].y); xv[3] = bf_hi(xq[q].y);
            xv[4] = bf_lo(xq[q].z); xv[5] = bf_hi(xq[q].z);
            xv[6] = bf_lo(xq[q].w); xv[7] = bf_hi(xq[q].w);
#pragma unroll
            for (int h = 0; h < 8; ++h) {
                const int k = q * 8 + h;
                const f32x4 w = *(const f32x4*)(W + ((size_t)j * 32 + k) * 64 + c4 * 4);
                acc.x = fmaf(xv[h], w.x, acc.x);
                acc.y = fmaf(xv[h], w.y, acc.y);
                acc.z = fmaf(xv[h], w.z, acc.z);
                acc.w = fmaf(xv[h], w.w, acc.w);
            }
        }
    }

    __builtin_nontemporal_store(acc, (f32x4*)(y + (size_t)node * 64 + c4 * 4));

    float sx = acc.x, sy = acc.y, sz = acc.z, sw = acc.w;
    float qx = acc.x * acc.x, qy = acc.y * acc.y, qz = acc.z * acc.z, qw = acc.w * acc.w;
#pragma unroll
    for (int off = 16; off <= 32; off <<= 1) {
        sx += __shfl_xor(sx, off, 64);  sy += __shfl_xor(sy, off, 64);
        sz += __shfl_xor(sz, off, 64);  sw += __shfl_xor(sw, off, 64);
        qx += __shfl_xor(qx, off, 64);  qy += __shfl_xor(qy, off, 64);
        qz += __shfl_xor(qz, off, 64);  qw += __shfl_xor(qw, off, 64);
    }
    if ((threadIdx.x & 63) < 16) {
        float* buf = stats + (blockIdx.x & (NBUF - 1)) * (2 * 64);
        atomicAdd(&buf[c4 * 4 + 0], sx);
        atomicAdd(&buf[c4 * 4 + 1], sy);
        atomicAdd(&buf[c4 * 4 + 2], sz);
        atomicAdd(&buf[c4 * 4 + 3], sw);
        atomicAdd(&buf[64 + c4 * 4 + 0], qx);
        atomicAdd(&buf[64 + c4 * 4 + 1], qy);
        atomicAdd(&buf[64 + c4 * 4 + 2], qz);
        atomicAdd(&buf[64 + c4 * 4 + 3], qw);
    }
}

// ---------------------------------------------------------------------------
// Fused BN-finalize (per-block recompute) + affine + ReLU + 8-sibling maxpool.
// ---------------------------------------------------------------------------
template<int COUT, bool BF16OUT>
__global__ void __launch_bounds__(256) pool_fin_kernel(
    const float* __restrict__ y, const float* __restrict__ stats,
    const float* __restrict__ gamma, const float* __restrict__ beta,
    void* __restrict__ xout, float invN, int total2)
{
    __shared__ float ss[2 * COUT];
    if (threadIdx.x < COUT) {
        const int c = threadIdx.x;
        float s = 0.f, q = 0.f;
        for (int b = 0; b < NBUF; ++b) {
            s += stats[b * 2 * COUT + c];
            q += stats[b * 2 * COUT + COUT + c];
        }
        const float mean = s * invN;
        const float var  = fmaf(-mean, mean, q * invN);
        const float sc   = gamma[c] * rsqrtf(var + BN_EPS);
        ss[c]        = sc;
        ss[COUT + c] = fmaf(-mean, sc, beta[c]);
    }
    __syncthreads();

    const int t = blockIdx.x * 256 + threadIdx.x;
    if (t >= total2) return;
    const int p  = t / (COUT / 2);
    const int c2 = (t % (COUT / 2)) * 2;
    const float sc0 = ss[c2],     sh0 = ss[COUT + c2];
    const float sc1 = ss[c2 + 1], sh1 = ss[COUT + c2 + 1];
    const float* yr = y + (size_t)p * 8 * COUT + c2;
    float m0 = -3.4e38f, m1 = -3.4e38f;
#pragma unroll
    for (int i = 0; i < 8; ++i) {
        const f32x2 v = __builtin_nontemporal_load((const f32x2*)(yr + i * COUT));
        m0 = fmaxf(m0, fmaf(v.x, sc0, sh0));
        m1 = fmaxf(m1, fmaf(v.y, sc1, sh1));
    }
    m0 = fmaxf(m0, 0.f);
    m1 = fmaxf(m1, 0.f);
    if (BF16OUT) {
        ((unsigned*)xout)[t] = pack_bf16(m0, m1);
    } else {
        f32x2 r = { m0, m1 };
        ((f32x2*)xout)[t] = r;
    }
}

// ---------------------------------------------------------------------------
// octree2voxel scatter with transpose: out[b][c][i][j][k] = x3[n][c], r=vox[n]
// ---------------------------------------------------------------------------
__global__ void __launch_bounds__(256) scatter_kernel(
    const float* __restrict__ x3, const int* __restrict__ vox,
    float* __restrict__ out)
{
    const int t = blockIdx.x * 256 + threadIdx.x;  // 1024*64 threads
    const int n = t >> 6, c = t & 63;
    const int r = vox[n];
    out[((r >> 9) << 15) + (c << 9) + (r & 511)] = x3[t];
}

extern "C" void kernel_launch(void* const* d_in, const int* in_sizes, int n_in,
                              void* d_out, int out_size, void* d_ws, size_t ws_size,
                              hipStream_t stream)
{
    const float* data = (const float*)d_in[0];
    const float* W0   = (const float*)d_in[1];
    const float* g0   = (const float*)d_in[2];
    const float* b0   = (const float*)d_in[3];
    const float* W1   = (const float*)d_in[4];
    const float* g1   = (const float*)d_in[5];
    const float* b1   = (const float*)d_in[6];
    const float* W2   = (const float*)d_in[7];
    const float* g2   = (const float*)d_in[8];
    const float* b2   = (const float*)d_in[9];
    const int* neigh0 = (const int*)d_in[10];
    const int* neigh1 = (const int*)d_in[11];
    const int* neigh2 = (const int*)d_in[12];
    const int* vox    = (const int*)d_in[13];

    const int N6 = 524288, N5 = 65536, N4 = 8192, N3 = 1024;

    float* ws = (float*)d_ws;
    const size_t off_y0  = 0;                                 // N6*16
    const size_t off_xb1 = off_y0 + (size_t)N6 * 16;          // N5*8  (bf16 x1)
    const size_t off_y1  = off_xb1 + (size_t)N5 * 8;          // N5*32
    const size_t off_xb0 = off_y1;                            // N6*2  (bf16 x0, alias)
    const size_t off_xb2 = off_y1 + (size_t)N5 * 32;          // N4*16 (bf16 x2)
    const size_t off_y2  = off_xb2 + (size_t)N4 * 16;         // N4*64
    const size_t off_x3  = off_y2 + (size_t)N4 * 64;          // N3*64
    const size_t off_st0 = off_x3 + (size_t)N3 * 64;          // NBUF*2*16
    const size_t off_st1 = off_st0 + NBUF * 2 * 16;           // NBUF*2*32
    const size_t off_st2 = off_st1 + NBUF * 2 * 32;           // NBUF*2*64

    (void)hipMemsetAsync(ws + off_st0, 0, (size_t)(NBUF * 2 * (16 + 32 + 64)) * sizeof(float), stream);

    // stage 0: cast data -> bf16 table (4MB), conv with L1-bypass gathers
    cast_bf16_kernel<<<N6 / 256, 256, 0, stream>>>(
        (const f32x4*)data, (u32x2*)(ws + off_xb0), N6);
    conv0_kernel<<<N6 / 256, 256, 0, stream>>>(
        (const unsigned long long*)(ws + off_xb0), neigh0, W0, ws + off_y0, ws + off_st0);
    pool_fin_kernel<16, true><<<(N5 * 8) / 256, 256, 0, stream>>>(
        ws + off_y0, ws + off_st0, g0, b0, ws + off_xb1, 1.f / N6, N5 * 8);

    // stage 1
    conv1_kernel<<<dim3(N5 / 256, 4), 256, 0, stream>>>(
        (const u32x4*)(ws + off_xb1), neigh1, W1, ws + off_y1, ws + off_st1);
    pool_fin_kernel<32, true><<<(N4 * 16) / 256, 256, 0, stream>>>(
        ws + off_y1, ws + off_st1, g1, b1, ws + off_xb2, 1.f / N5, N4 * 16);

    // stage 2
    conv2_kernel<<<N4 / 16, 256, 0, stream>>>(
        (const u32x4*)(ws + off_xb2), neigh2, W2, ws + off_y2, ws + off_st2);
    pool_fin_kernel<64, false><<<(N3 * 32) / 256, 256, 0, stream>>>(
        ws + off_y2, ws + off_st2, g2, b2, ws + off_x3, 1.f / N4, N3 * 32);

    // octree2voxel
    (void)hipMemsetAsync(d_out, 0, (size_t)out_size * sizeof(float), stream);
    scatter_kernel<<<(N3 * 64) / 256, 256, 0, stream>>>(ws + off_x3, vox, (float*)d_out);
}